// Round 10
// baseline (1628.917 us; speedup 1.0000x reference)
//
#include <hip/hip_runtime.h>

#define NROWS 65536
#define FEA   512
#define MEM   2000
#define MEMP  2048
#define LAMBDA 0.0025f
#define EPS    1e-12f

#define PLX ((long)NROWS * FEA)   // elements per x plane
#define PLW ((long)MEMP * FEA)    // elements per W plane

typedef unsigned short ushort_t;
typedef __attribute__((ext_vector_type(8))) short bf16x8;
typedef __attribute__((ext_vector_type(4))) float f32x4;

// ---------- bf16 split helpers (RNE) ----------
__device__ inline ushort_t f2bf(float f) {
  unsigned int u = __float_as_uint(f);
  unsigned int r = (u + 0x7FFFu + ((u >> 16) & 1u)) >> 16;
  return (ushort_t)r;
}
__device__ inline float bf2f(ushort_t h) {
  return __uint_as_float(((unsigned int)h) << 16);
}

__device__ inline void gload_lds16(const void* g, void* l) {
  __builtin_amdgcn_global_load_lds(
      (const __attribute__((address_space(1))) unsigned int*)g,
      (__attribute__((address_space(3))) unsigned int*)l, 16, 0, 0);
}

// ------------------------------------------------------------------
// K0a: split x (fp32) -> xh, xl bf16 planes (stored in out region)
// ------------------------------------------------------------------
__global__ __launch_bounds__(256) void split_x(const float* __restrict__ x,
                                               ushort_t* __restrict__ xpl) {
  const long n4 = PLX / 4;
  long i = (long)blockIdx.x * 256 + threadIdx.x;
  const long stride = (long)gridDim.x * 256;
  for (; i < n4; i += stride) {
    float4 v = ((const float4*)x)[i];
    float f[4] = {v.x, v.y, v.z, v.w};
    ushort_t hh[4], ll[4];
#pragma unroll
    for (int j = 0; j < 4; ++j) {
      hh[j] = f2bf(f[j]);
      ll[j] = f2bf(f[j] - bf2f(hh[j]));
    }
    ushort4 h; h.x = hh[0]; h.y = hh[1]; h.z = hh[2]; h.w = hh[3];
    ushort4 l; l.x = ll[0]; l.y = ll[1]; l.z = ll[2]; l.w = ll[3];
    ((ushort4*)xpl)[i] = h;
    ((ushort4*)(xpl + PLX))[i] = l;
  }
}

// ------------------------------------------------------------------
// K0b: split W -> wh, wl planes, padded to 2048 rows (zeros)
// ------------------------------------------------------------------
__global__ __launch_bounds__(256) void split_w(const float* __restrict__ W,
                                               ushort_t* __restrict__ wpl) {
  long i = (long)blockIdx.x * 256 + threadIdx.x;
  if (i >= PLW / 4) return;
  long row = i / (FEA / 4);
  ushort4 h = {0, 0, 0, 0}, l = {0, 0, 0, 0};
  if (row < MEM) {
    float4 v = ((const float4*)W)[i];
    float f[4] = {v.x, v.y, v.z, v.w};
    ushort_t hh[4], ll[4];
#pragma unroll
    for (int j = 0; j < 4; ++j) {
      hh[j] = f2bf(f[j]);
      ll[j] = f2bf(f[j] - bf2f(hh[j]));
    }
    h.x = hh[0]; h.y = hh[1]; h.z = hh[2]; h.w = hh[3];
    l.x = ll[0]; l.y = ll[1]; l.z = ll[2]; l.w = ll[3];
  }
  ((ushort4*)wpl)[i] = h;
  ((ushort4*)(wpl + PLW))[i] = l;
}

// ------------------------------------------------------------------
// K1: S = x @ W^T, split-bf16 (3 products), 256x256 tile, BK=32.
// 16x16x32 MFMA, conflict-free lane map (r9-proven). A in ring-3
// (96 KB) with REGISTER PREFETCH: A-frags(t+1) ds_read during region
// t's MFMAs, waited only in region t+1. B ring-2 (64 KB) convoy-read.
// LDS total 160 KB. Per-region: {issue B(t+1); issue A(t+3);
// convoy B(t); prefetch A(t+1)->regs; 96 MFMA; lgkm0; vmcnt(4); bar}.
// Slot: [256 rows][128 B] = 2 planes x 4 k-octets; phys = c^(row&7).
// ------------------------------------------------------------------
struct AFrags { bf16x8 a[8][2]; };

__device__ __forceinline__ void stageOp(const ushort_t* __restrict__ pl0,
                                        long planeStride, long row0, int t,
                                        int tid, ushort_t* dst /*slot base*/) {
#pragma unroll
  for (int i = 0; i < 4; ++i) {
    int id = i * 512 + tid;          // 0..2047 16B-positions
    int row = id >> 3;               // 0..255
    int ps = id & 7;                 // physical chunk
    int ls = ps ^ (row & 7);         // logical chunk (involution)
    int pl = ls >> 2, ko = ls & 3;
    long goff = (long)pl * planeStride + (row0 + row) * FEA + t * 32 + ko * 8;
    gload_lds16(pl0 + goff, dst + (size_t)id * 8);
  }
}

__device__ __forceinline__ void read_afrags(const ushort_t* As, int l15,
                                            int lq, int wm, AFrags& f) {
#pragma unroll
  for (int mf = 0; mf < 8; ++mf) {
    int r = wm * 128 + mf * 16 + l15;
    int rx = r & 7;
#pragma unroll
    for (int pl = 0; pl < 2; ++pl)
      f.a[mf][pl] = *(const bf16x8*)(As + r * 64 + ((((pl << 2) + lq) ^ rx) * 8));
  }
}

__device__ __forceinline__ void read_bfrags(const ushort_t* Bs, int l15,
                                            int lq, int wn, bf16x8 (&b)[4][2]) {
#pragma unroll
  for (int nf = 0; nf < 4; ++nf) {
    int r = wn * 64 + nf * 16 + l15;
    int rx = r & 7;
#pragma unroll
    for (int pl = 0; pl < 2; ++pl)
      b[nf][pl] = *(const bf16x8*)(Bs + r * 64 + ((((pl << 2) + lq) ^ rx) * 8));
  }
}

__device__ __forceinline__ void mfma96(const AFrags& f, const bf16x8 (&b)[4][2],
                                       f32x4 (&acc)[8][4]) {
  __builtin_amdgcn_s_setprio(1);
#pragma unroll
  for (int mf = 0; mf < 8; ++mf)
#pragma unroll
    for (int nf = 0; nf < 4; ++nf)
      acc[mf][nf] = __builtin_amdgcn_mfma_f32_16x16x32_bf16(
          f.a[mf][0], b[nf][0], acc[mf][nf], 0, 0, 0);
#pragma unroll
  for (int mf = 0; mf < 8; ++mf)
#pragma unroll
    for (int nf = 0; nf < 4; ++nf)
      acc[mf][nf] = __builtin_amdgcn_mfma_f32_16x16x32_bf16(
          f.a[mf][0], b[nf][1], acc[mf][nf], 0, 0, 0);
#pragma unroll
  for (int mf = 0; mf < 8; ++mf)
#pragma unroll
    for (int nf = 0; nf < 4; ++nf)
      acc[mf][nf] = __builtin_amdgcn_mfma_f32_16x16x32_bf16(
          f.a[mf][1], b[nf][0], acc[mf][nf], 0, 0, 0);
  __builtin_amdgcn_s_setprio(0);
}

__device__ __forceinline__ void region(
    int t, int tid, int l15, int lq, int wm, int wn,
    const ushort_t* __restrict__ xpl, const ushort_t* __restrict__ wpl,
    long rm0, long cn0, ushort_t* ldsA, ushort_t* ldsB,
    AFrags& cur, AFrags& nxt, f32x4 (&acc)[8][4]) {
  // issue next stages (B first: it must retire at this region's vmcnt)
  if (t <= 14)
    stageOp(wpl, PLW, cn0, t + 1, tid, ldsB + (size_t)((t + 1) & 1) * 16384);
  if (t <= 12)
    stageOp(xpl, PLX, rm0, t + 3, tid, ldsA + (size_t)((t + 3) % 3) * 16384);

  bf16x8 b[4][2];
  read_bfrags(ldsB + (size_t)(t & 1) * 16384, l15, lq, wn, b);
  if (t <= 14)  // prefetch next A-frags; lgkm wait deferred to next region
    read_afrags(ldsA + (size_t)((t + 1) % 3) * 16384, l15, lq, wm, nxt);

  mfma96(cur, b, acc);

  if (t <= 14) {
    asm volatile("s_waitcnt lgkmcnt(0)" ::: "memory");  // cross-wave WAR fence
    if (t <= 12) asm volatile("s_waitcnt vmcnt(4)" ::: "memory");
    else         asm volatile("s_waitcnt vmcnt(0)" ::: "memory");
    asm volatile("s_barrier" ::: "memory");
  }
}

__global__ __launch_bounds__(512, 2) void gemm_mfma8(
    const ushort_t* __restrict__ xpl, const ushort_t* __restrict__ wpl,
    float* __restrict__ S) {
  __shared__ alignas(16) ushort_t ldsA[3 * 16384];  // 96 KB, ring-3
  __shared__ alignas(16) ushort_t ldsB[2 * 16384];  // 64 KB, ring-2

  const int tid = threadIdx.x;
  const int wid = tid >> 6, lane = tid & 63;
  const int l15 = lane & 15, lq = lane >> 4;   // 16x16 lane map
  const int wm = wid >> 2, wn = wid & 3;       // 2M x 4N waves

  // XCD-chunked bijective swizzle (2048 wgs): proven 197 MB fetch
  int wg = blockIdx.x;
  int xcd = wg & 7, idx = wg >> 3;
  const int mt = xcd * 32 + (idx >> 3);
  const int nt = idx & 7;
  const long rm0 = (long)mt * 256;
  const long cn0 = (long)nt * 256;

  f32x4 acc[8][4] = {};
  AFrags fE, fO;

  // prologue: A(0),B(0),A(1); prefetch frags(0); then A(2) in flight
  stageOp(xpl, PLX, rm0, 0, tid, ldsA);
  stageOp(wpl, PLW, cn0, 0, tid, ldsB);
  stageOp(xpl, PLX, rm0, 1, tid, ldsA + 16384);
  asm volatile("s_waitcnt vmcnt(0)" ::: "memory");
  asm volatile("s_barrier" ::: "memory");
  read_afrags(ldsA, l15, lq, wm, fE);
  asm volatile("s_waitcnt lgkmcnt(0)" ::: "memory");  // before A(3) overwrites slot0
  asm volatile("s_barrier" ::: "memory");
  stageOp(xpl, PLX, rm0, 2, tid, ldsA + 2 * 16384);   // 4 outstanding

  for (int tt = 0; tt < 8; ++tt) {
    region(2 * tt,     tid, l15, lq, wm, wn, xpl, wpl, rm0, cn0, ldsA, ldsB, fE, fO, acc);
    region(2 * tt + 1, tid, l15, lq, wm, wn, xpl, wpl, rm0, cn0, ldsA, ldsB, fO, fE, acc);
  }

  // epilogue: 16x16 C/D layout col = lane&15, row = (lane>>4)*4 + reg
#pragma unroll
  for (int mf = 0; mf < 8; ++mf)
#pragma unroll
    for (int nf = 0; nf < 4; ++nf) {
      int col = (int)cn0 + wn * 64 + nf * 16 + l15;
      if (col < MEM) {
        long rbase = rm0 + wm * 128 + mf * 16 + lq * 4;
#pragma unroll
        for (int r = 0; r < 4; ++r)
          S[(rbase + r) * MEM + col] = acc[mf][nf][r];
      }
    }
}

// ------------------------------------------------------------------
// Fallback fp32 GEMM (used only if ws too small)
// ------------------------------------------------------------------
#define BKF 32
__global__ __launch_bounds__(256) void gemm_scores(
    const float* __restrict__ x, const float* __restrict__ Wt,
    float* __restrict__ S) {
  __shared__ float xs[BKF][129];
  __shared__ float ws[BKF][129];
  const int tid = threadIdx.x;
  const int rm0 = blockIdx.x * 128;
  const int cn0 = blockIdx.y * 128;
  const int tx = tid & 15, ty = tid >> 4;
  const int sr = tid >> 3, kq = tid & 7;
  float acc[8][8];
#pragma unroll
  for (int i = 0; i < 8; ++i)
#pragma unroll
    for (int j = 0; j < 8; ++j) acc[i][j] = 0.f;
  for (int k0 = 0; k0 < FEA; k0 += BKF) {
#pragma unroll
    for (int b = 0; b < 4; ++b) {
      const int row = sr + 32 * b;
      float4 v = *(const float4*)(x + (size_t)(rm0 + row) * FEA + k0 + kq * 4);
      xs[kq * 4 + 0][row] = v.x; xs[kq * 4 + 1][row] = v.y;
      xs[kq * 4 + 2][row] = v.z; xs[kq * 4 + 3][row] = v.w;
      int wr = cn0 + row; wr = (wr < MEM) ? wr : (MEM - 1);
      float4 u = *(const float4*)(Wt + (size_t)wr * FEA + k0 + kq * 4);
      ws[kq * 4 + 0][row] = u.x; ws[kq * 4 + 1][row] = u.y;
      ws[kq * 4 + 2][row] = u.z; ws[kq * 4 + 3][row] = u.w;
    }
    __syncthreads();
#pragma unroll 8
    for (int k = 0; k < BKF; ++k) {
      float a[8], bb[8];
      float4 t0 = *(const float4*)&xs[k][4 * ty];
      float4 t1 = *(const float4*)&xs[k][64 + 4 * ty];
      a[0] = t0.x; a[1] = t0.y; a[2] = t0.z; a[3] = t0.w;
      a[4] = t1.x; a[5] = t1.y; a[6] = t1.z; a[7] = t1.w;
      float4 u0 = *(const float4*)&ws[k][4 * tx];
      float4 u1 = *(const float4*)&ws[k][64 + 4 * tx];
      bb[0] = u0.x; bb[1] = u0.y; bb[2] = u0.z; bb[3] = u0.w;
      bb[4] = u1.x; bb[5] = u1.y; bb[6] = u1.z; bb[7] = u1.w;
#pragma unroll
      for (int i = 0; i < 8; ++i)
#pragma unroll
        for (int j = 0; j < 8; ++j)
          acc[i][j] = fmaf(a[i], bb[j], acc[i][j]);
    }
    __syncthreads();
  }
#pragma unroll
  for (int i = 0; i < 8; ++i) {
    const int row = rm0 + ((i < 4) ? (4 * ty + i) : (64 + 4 * ty + (i - 4)));
    const int c0 = cn0 + 4 * tx;
    const int c1 = cn0 + 64 + 4 * tx;
    if (c0 < MEM) {
      float4 v; v.x = acc[i][0]; v.y = acc[i][1]; v.z = acc[i][2]; v.w = acc[i][3];
      *(float4*)(S + (size_t)row * MEM + c0) = v;
    }
    if (c1 < MEM) {
      float4 v; v.x = acc[i][4]; v.y = acc[i][5]; v.z = acc[i][6]; v.w = acc[i][7];
      *(float4*)(S + (size_t)row * MEM + c1) = v;
    }
  }
}

// ------------------------------------------------------------------
// K2: softmax -> hard shrink -> renorm -> write att + sparse out
// ------------------------------------------------------------------
__global__ __launch_bounds__(512) void softmax_shrink_out(
    const float* __restrict__ Wt, float* __restrict__ out,
    float* __restrict__ att /* raw scores on entry */) {
  __shared__ float sl[8 * MEM];
  const int tid = threadIdx.x;
  const int r0 = blockIdx.x * 8;
  {
    const float* Sblk = att + (size_t)r0 * MEM;
#pragma unroll
    for (int jj = 0; jj < 8; ++jj) {
      int q = tid + 512 * jj;
      if (q < (8 * MEM) / 4) {
        float4 v = *(const float4*)(Sblk + 4 * q);
        *(float4*)&sl[4 * q] = v;
      }
    }
  }
  __syncthreads();
  const int w = tid >> 6;
  const int l = tid & 63;
  float* row_lds = &sl[w * MEM];
  const int grow = r0 + w;

  float m = -INFINITY;
  for (int j = 0; j < 32; ++j) {
    int c = l + 64 * j;
    if (c < MEM) m = fmaxf(m, row_lds[c]);
  }
#pragma unroll
  for (int off = 32; off; off >>= 1) m = fmaxf(m, __shfl_xor(m, off));

  float s = 0.f;
  for (int j = 0; j < 32; ++j) {
    int c = l + 64 * j;
    if (c < MEM) {
      float e = expf(row_lds[c] - m);
      row_lds[c] = e;
      s += e;
    }
  }
#pragma unroll
  for (int off = 32; off; off >>= 1) s += __shfl_xor(s, off);

  float qs = 0.f;
  for (int j = 0; j < 32; ++j) {
    int c = l + 64 * j;
    if (c < MEM) {
      float p = row_lds[c] / s;
      float d = p - LAMBDA;
      float q = fmaxf(d, 0.f) * p / (fabsf(d) + EPS);
      row_lds[c] = q;
      qs += q;
    }
  }
#pragma unroll
  for (int off = 32; off; off >>= 1) qs += __shfl_xor(qs, off);
  const float denom = fmaxf(qs, EPS);

  float4 oa0 = {0.f, 0.f, 0.f, 0.f};
  float4 oa1 = {0.f, 0.f, 0.f, 0.f};
  for (int j = 0; j < 32; ++j) {
    int c = l + 64 * j;
    float a = 0.f;
    if (c < MEM) {
      a = row_lds[c] / denom;
      att[(size_t)grow * MEM + c] = a;
    }
    unsigned long long msk = __ballot(a > 0.f);
    while (msk) {
      int b = __ffsll(msk) - 1;
      msk &= msk - 1;
      float av = __shfl(a, b);
      int cc = b + 64 * j;
      const float* wp = Wt + (size_t)cc * FEA;
      float4 w0 = *(const float4*)(wp + 4 * l);
      float4 w1 = *(const float4*)(wp + 256 + 4 * l);
      oa0.x = fmaf(av, w0.x, oa0.x); oa0.y = fmaf(av, w0.y, oa0.y);
      oa0.z = fmaf(av, w0.z, oa0.z); oa0.w = fmaf(av, w0.w, oa0.w);
      oa1.x = fmaf(av, w1.x, oa1.x); oa1.y = fmaf(av, w1.y, oa1.y);
      oa1.z = fmaf(av, w1.z, oa1.z); oa1.w = fmaf(av, w1.w, oa1.w);
    }
  }
  float* op = out + (size_t)grow * FEA;
  *(float4*)(op + 4 * l) = oa0;
  *(float4*)(op + 256 + 4 * l) = oa1;
}

// ------------------------------------------------------------------
extern "C" void kernel_launch(void* const* d_in, const int* in_sizes, int n_in,
                              void* d_out, int out_size, void* d_ws, size_t ws_size,
                              hipStream_t stream) {
  (void)in_sizes; (void)n_in; (void)out_size;
  const float* x = (const float*)d_in[0];
  const float* W = (const float*)d_in[1];
  float* out = (float*)d_out;
  float* att = (float*)d_out + (size_t)NROWS * FEA;

  const size_t w_need = (size_t)PLW * 2 * sizeof(ushort_t);  // 4 MB
  if (ws_size >= w_need) {
    ushort_t* xpl = (ushort_t*)d_out;  // out region: exactly fits 2 x-planes
    ushort_t* wpl = (ushort_t*)d_ws;
    split_x<<<2048, 256, 0, stream>>>(x, xpl);
    split_w<<<(int)(PLW / 4 / 256), 256, 0, stream>>>(W, wpl);
    gemm_mfma8<<<2048, 512, 0, stream>>>(xpl, wpl, att);
  } else {
    dim3 g1(NROWS / 128, (MEM + 127) / 128);
    gemm_scores<<<g1, 256, 0, stream>>>(x, W, att);
  }
  softmax_shrink_out<<<NROWS / 8, 512, 0, stream>>>(W, out, att);
}

// Round 11
// 715.052 us; speedup vs baseline: 2.2780x; 2.2780x over previous
//
#include <hip/hip_runtime.h>

#define NROWS 65536
#define FEA   512
#define MEM   2000
#define MEMP  2048
#define LAMBDA 0.0025f
#define EPS    1e-12f

#define PLX ((long)NROWS * FEA)   // elements per x plane
#define PLW ((long)MEMP * FEA)    // elements per W plane

typedef unsigned short ushort_t;
typedef __attribute__((ext_vector_type(8))) short bf16x8;
typedef __attribute__((ext_vector_type(4))) float f32x4;

// ---------- bf16 split helpers (RNE) ----------
__device__ inline ushort_t f2bf(float f) {
  unsigned int u = __float_as_uint(f);
  unsigned int r = (u + 0x7FFFu + ((u >> 16) & 1u)) >> 16;
  return (ushort_t)r;
}
__device__ inline float bf2f(ushort_t h) {
  return __uint_as_float(((unsigned int)h) << 16);
}

__device__ inline void gload_lds16(const void* g, void* l) {
  __builtin_amdgcn_global_load_lds(
      (const __attribute__((address_space(1))) unsigned int*)g,
      (__attribute__((address_space(3))) unsigned int*)l, 16, 0, 0);
}

// ------------------------------------------------------------------
// K0a: split x (fp32) -> xh, xl bf16 planes (stored in out region)
// ------------------------------------------------------------------
__global__ __launch_bounds__(256) void split_x(const float* __restrict__ x,
                                               ushort_t* __restrict__ xpl) {
  const long n4 = PLX / 4;
  long i = (long)blockIdx.x * 256 + threadIdx.x;
  const long stride = (long)gridDim.x * 256;
  for (; i < n4; i += stride) {
    float4 v = ((const float4*)x)[i];
    float f[4] = {v.x, v.y, v.z, v.w};
    ushort_t hh[4], ll[4];
#pragma unroll
    for (int j = 0; j < 4; ++j) {
      hh[j] = f2bf(f[j]);
      ll[j] = f2bf(f[j] - bf2f(hh[j]));
    }
    ushort4 h; h.x = hh[0]; h.y = hh[1]; h.z = hh[2]; h.w = hh[3];
    ushort4 l; l.x = ll[0]; l.y = ll[1]; l.z = ll[2]; l.w = ll[3];
    ((ushort4*)xpl)[i] = h;
    ((ushort4*)(xpl + PLX))[i] = l;
  }
}

// ------------------------------------------------------------------
// K0b: split W -> wh, wl planes, padded to 2048 rows (zeros)
// ------------------------------------------------------------------
__global__ __launch_bounds__(256) void split_w(const float* __restrict__ W,
                                               ushort_t* __restrict__ wpl) {
  long i = (long)blockIdx.x * 256 + threadIdx.x;
  if (i >= PLW / 4) return;
  long row = i / (FEA / 4);
  ushort4 h = {0, 0, 0, 0}, l = {0, 0, 0, 0};
  if (row < MEM) {
    float4 v = ((const float4*)W)[i];
    float f[4] = {v.x, v.y, v.z, v.w};
    ushort_t hh[4], ll[4];
#pragma unroll
    for (int j = 0; j < 4; ++j) {
      hh[j] = f2bf(f[j]);
      ll[j] = f2bf(f[j] - bf2f(hh[j]));
    }
    h.x = hh[0]; h.y = hh[1]; h.z = hh[2]; h.w = hh[3];
    l.x = ll[0]; l.y = ll[1]; l.z = ll[2]; l.w = ll[3];
  }
  ((ushort4*)wpl)[i] = h;
  ((ushort4*)(wpl + PLW))[i] = l;
}

// ------------------------------------------------------------------
// K1: S = x @ W^T, split-bf16 (3 products), 256x256 tile, BK=32.
// = round-9 kernel (395us, conflicts 0, FETCH 197MB) with addressing
// hoisted: rx = l15&7 is lane-only, so ALL ds_read addresses are one
// of 4 precomputed per-lane bases + compile-time immediate; stage
// offsets are per-lane constants + uniform t*32. t-loop unrolled x2.
// LDS bytes: A slot0 @0, A slot1 @32K, B slot0 @64K, B slot1 @96K.
// ------------------------------------------------------------------
__global__ __launch_bounds__(512, 2) void gemm_mfma9(
    const ushort_t* __restrict__ xpl, const ushort_t* __restrict__ wpl,
    float* __restrict__ S) {
  __shared__ alignas(16) ushort_t lds[65536];  // 128 KB

  const int tid = threadIdx.x;
  const int wid = tid >> 6, lane = tid & 63;
  const int l15 = lane & 15, lq = lane >> 4, rx = l15 & 7;
  const int wm = wid >> 2, wn = wid & 3;       // 2M x 4N waves

  // XCD-chunked bijective swizzle (2048 wgs): proven 197 MB fetch
  int wg = blockIdx.x;
  int xcd = wg & 7, idx = wg >> 3;
  const int mt = xcd * 32 + (idx >> 3);
  const int nt = idx & 7;
  const long rm0 = (long)mt * 256;
  const long cn0 = (long)nt * 256;

  // --- precomputed per-lane LDS read bases (ushort units) ---
  const int aU0 = (wm * 128 + l15) * 64 + ((lq ^ rx) * 8);
  const int aU1 = aU0 ^ 32;                    // plane-1: byte ^64
  const int bU0 = 32768 + (wn * 64 + l15) * 64 + ((lq ^ rx) * 8);
  const int bU1 = bU0 ^ 32;

  // --- precomputed per-lane stage offsets ---
  int sDst[4], sOffX[4], sOffW[4];
#pragma unroll
  for (int i = 0; i < 4; ++i) {
    int id = i * 512 + tid;          // 16B-position 0..2047
    int row = id >> 3;
    int ls = (id & 7) ^ (row & 7);   // logical chunk (involution)
    sDst[i] = id * 8;                // ushort units within a slot
    sOffX[i] = (ls >> 2) * (int)PLX + row * FEA + (ls & 3) * 8;
    sOffW[i] = (ls >> 2) * (int)PLW + row * FEA + (ls & 3) * 8;
  }
  const ushort_t* xb = xpl + rm0 * FEA;
  const ushort_t* wb = wpl + cn0 * FEA;

  f32x4 acc[8][4] = {};

  // stage K-tile t into slot sl (0/1): A at sl*16384, B at 32768+sl*16384
  auto stage = [&](int t, int sl) {
    const ushort_t* xs = xb + t * 32;
    const ushort_t* ws = wb + t * 32;
    ushort_t* dA = (ushort_t*)lds + sl * 16384;
    ushort_t* dB = (ushort_t*)lds + 32768 + sl * 16384;
#pragma unroll
    for (int i = 0; i < 4; ++i) gload_lds16(xs + sOffX[i], dA + sDst[i]);
#pragma unroll
    for (int i = 0; i < 4; ++i) gload_lds16(ws + sOffW[i], dB + sDst[i]);
  };

  // one K-tile: SLOT is a compile-time literal
  auto tile = [&](int t, int SLOT, bool last) {
    const ushort_t* L = (const ushort_t*)lds;
    const int so = SLOT * 16384;

    // B fragments (immediate-offset ds_reads off 2 bases)
    bf16x8 b[4][2];
#pragma unroll
    for (int nf = 0; nf < 4; ++nf) {
      b[nf][0] = *(const bf16x8*)(L + bU0 + so + nf * 1024);
      b[nf][1] = *(const bf16x8*)(L + bU1 + so + nf * 1024);
    }
    if (!last) stage(t + 1, SLOT ^ 1);

    // two half-passes over mf to bound live A regs
#pragma unroll
    for (int h = 0; h < 2; ++h) {
      bf16x8 a[4][2];
#pragma unroll
      for (int mi = 0; mi < 4; ++mi) {
        a[mi][0] = *(const bf16x8*)(L + aU0 + so + (h * 4 + mi) * 1024);
        a[mi][1] = *(const bf16x8*)(L + aU1 + so + (h * 4 + mi) * 1024);
      }
      __builtin_amdgcn_s_setprio(1);
#pragma unroll
      for (int mi = 0; mi < 4; ++mi)
#pragma unroll
        for (int nf = 0; nf < 4; ++nf)
          acc[h * 4 + mi][nf] = __builtin_amdgcn_mfma_f32_16x16x32_bf16(
              a[mi][0], b[nf][0], acc[h * 4 + mi][nf], 0, 0, 0);
#pragma unroll
      for (int mi = 0; mi < 4; ++mi)
#pragma unroll
        for (int nf = 0; nf < 4; ++nf)
          acc[h * 4 + mi][nf] = __builtin_amdgcn_mfma_f32_16x16x32_bf16(
              a[mi][0], b[nf][1], acc[h * 4 + mi][nf], 0, 0, 0);
#pragma unroll
      for (int mi = 0; mi < 4; ++mi)
#pragma unroll
        for (int nf = 0; nf < 4; ++nf)
          acc[h * 4 + mi][nf] = __builtin_amdgcn_mfma_f32_16x16x32_bf16(
              a[mi][1], b[nf][0], acc[h * 4 + mi][nf], 0, 0, 0);
      __builtin_amdgcn_s_setprio(0);
    }

    if (!last) {
      asm volatile("s_waitcnt vmcnt(0)" ::: "memory");
      asm volatile("s_barrier" ::: "memory");
    }
  };

  // prologue: stage K-tile 0 into slot 0
  stage(0, 0);
  asm volatile("s_waitcnt vmcnt(0)" ::: "memory");
  asm volatile("s_barrier" ::: "memory");

  for (int tt = 0; tt < 7; ++tt) {
    tile(2 * tt, 0, false);
    tile(2 * tt + 1, 1, false);
  }
  tile(14, 0, false);
  tile(15, 1, true);

  // epilogue: 16x16 C/D layout col = lane&15, row = (lane>>4)*4 + reg
#pragma unroll
  for (int mf = 0; mf < 8; ++mf)
#pragma unroll
    for (int nf = 0; nf < 4; ++nf) {
      int col = (int)cn0 + wn * 64 + nf * 16 + l15;
      if (col < MEM) {
        long rbase = rm0 + wm * 128 + mf * 16 + lq * 4;
#pragma unroll
        for (int r = 0; r < 4; ++r)
          S[(rbase + r) * MEM + col] = acc[mf][nf][r];
      }
    }
}

// ------------------------------------------------------------------
// Fallback fp32 GEMM (used only if ws too small)
// ------------------------------------------------------------------
#define BKF 32
__global__ __launch_bounds__(256) void gemm_scores(
    const float* __restrict__ x, const float* __restrict__ Wt,
    float* __restrict__ S) {
  __shared__ float xs[BKF][129];
  __shared__ float ws[BKF][129];
  const int tid = threadIdx.x;
  const int rm0 = blockIdx.x * 128;
  const int cn0 = blockIdx.y * 128;
  const int tx = tid & 15, ty = tid >> 4;
  const int sr = tid >> 3, kq = tid & 7;
  float acc[8][8];
#pragma unroll
  for (int i = 0; i < 8; ++i)
#pragma unroll
    for (int j = 0; j < 8; ++j) acc[i][j] = 0.f;
  for (int k0 = 0; k0 < FEA; k0 += BKF) {
#pragma unroll
    for (int b = 0; b < 4; ++b) {
      const int row = sr + 32 * b;
      float4 v = *(const float4*)(x + (size_t)(rm0 + row) * FEA + k0 + kq * 4);
      xs[kq * 4 + 0][row] = v.x; xs[kq * 4 + 1][row] = v.y;
      xs[kq * 4 + 2][row] = v.z; xs[kq * 4 + 3][row] = v.w;
      int wr = cn0 + row; wr = (wr < MEM) ? wr : (MEM - 1);
      float4 u = *(const float4*)(Wt + (size_t)wr * FEA + k0 + kq * 4);
      ws[kq * 4 + 0][row] = u.x; ws[kq * 4 + 1][row] = u.y;
      ws[kq * 4 + 2][row] = u.z; ws[kq * 4 + 3][row] = u.w;
    }
    __syncthreads();
#pragma unroll 8
    for (int k = 0; k < BKF; ++k) {
      float a[8], bb[8];
      float4 t0 = *(const float4*)&xs[k][4 * ty];
      float4 t1 = *(const float4*)&xs[k][64 + 4 * ty];
      a[0] = t0.x; a[1] = t0.y; a[2] = t0.z; a[3] = t0.w;
      a[4] = t1.x; a[5] = t1.y; a[6] = t1.z; a[7] = t1.w;
      float4 u0 = *(const float4*)&ws[k][4 * tx];
      float4 u1 = *(const float4*)&ws[k][64 + 4 * tx];
      bb[0] = u0.x; bb[1] = u0.y; bb[2] = u0.z; bb[3] = u0.w;
      bb[4] = u1.x; bb[5] = u1.y; bb[6] = u1.z; bb[7] = u1.w;
#pragma unroll
      for (int i = 0; i < 8; ++i)
#pragma unroll
        for (int j = 0; j < 8; ++j)
          acc[i][j] = fmaf(a[i], bb[j], acc[i][j]);
    }
    __syncthreads();
  }
#pragma unroll
  for (int i = 0; i < 8; ++i) {
    const int row = rm0 + ((i < 4) ? (4 * ty + i) : (64 + 4 * ty + (i - 4)));
    const int c0 = cn0 + 4 * tx;
    const int c1 = cn0 + 64 + 4 * tx;
    if (c0 < MEM) {
      float4 v; v.x = acc[i][0]; v.y = acc[i][1]; v.z = acc[i][2]; v.w = acc[i][3];
      *(float4*)(S + (size_t)row * MEM + c0) = v;
    }
    if (c1 < MEM) {
      float4 v; v.x = acc[i][4]; v.y = acc[i][5]; v.z = acc[i][6]; v.w = acc[i][7];
      *(float4*)(S + (size_t)row * MEM + c1) = v;
    }
  }
}

// ------------------------------------------------------------------
// K2: softmax -> hard shrink -> renorm -> write att + sparse out
// ------------------------------------------------------------------
__global__ __launch_bounds__(512) void softmax_shrink_out(
    const float* __restrict__ Wt, float* __restrict__ out,
    float* __restrict__ att /* raw scores on entry */) {
  __shared__ float sl[8 * MEM];
  const int tid = threadIdx.x;
  const int r0 = blockIdx.x * 8;
  {
    const float* Sblk = att + (size_t)r0 * MEM;
#pragma unroll
    for (int jj = 0; jj < 8; ++jj) {
      int q = tid + 512 * jj;
      if (q < (8 * MEM) / 4) {
        float4 v = *(const float4*)(Sblk + 4 * q);
        *(float4*)&sl[4 * q] = v;
      }
    }
  }
  __syncthreads();
  const int w = tid >> 6;
  const int l = tid & 63;
  float* row_lds = &sl[w * MEM];
  const int grow = r0 + w;

  float m = -INFINITY;
  for (int j = 0; j < 32; ++j) {
    int c = l + 64 * j;
    if (c < MEM) m = fmaxf(m, row_lds[c]);
  }
#pragma unroll
  for (int off = 32; off; off >>= 1) m = fmaxf(m, __shfl_xor(m, off));

  float s = 0.f;
  for (int j = 0; j < 32; ++j) {
    int c = l + 64 * j;
    if (c < MEM) {
      float e = expf(row_lds[c] - m);
      row_lds[c] = e;
      s += e;
    }
  }
#pragma unroll
  for (int off = 32; off; off >>= 1) s += __shfl_xor(s, off);

  float qs = 0.f;
  for (int j = 0; j < 32; ++j) {
    int c = l + 64 * j;
    if (c < MEM) {
      float p = row_lds[c] / s;
      float d = p - LAMBDA;
      float q = fmaxf(d, 0.f) * p / (fabsf(d) + EPS);
      row_lds[c] = q;
      qs += q;
    }
  }
#pragma unroll
  for (int off = 32; off; off >>= 1) qs += __shfl_xor(qs, off);
  const float denom = fmaxf(qs, EPS);

  float4 oa0 = {0.f, 0.f, 0.f, 0.f};
  float4 oa1 = {0.f, 0.f, 0.f, 0.f};
  for (int j = 0; j < 32; ++j) {
    int c = l + 64 * j;
    float a = 0.f;
    if (c < MEM) {
      a = row_lds[c] / denom;
      att[(size_t)grow * MEM + c] = a;
    }
    unsigned long long msk = __ballot(a > 0.f);
    while (msk) {
      int b = __ffsll(msk) - 1;
      msk &= msk - 1;
      float av = __shfl(a, b);
      int cc = b + 64 * j;
      const float* wp = Wt + (size_t)cc * FEA;
      float4 w0 = *(const float4*)(wp + 4 * l);
      float4 w1 = *(const float4*)(wp + 256 + 4 * l);
      oa0.x = fmaf(av, w0.x, oa0.x); oa0.y = fmaf(av, w0.y, oa0.y);
      oa0.z = fmaf(av, w0.z, oa0.z); oa0.w = fmaf(av, w0.w, oa0.w);
      oa1.x = fmaf(av, w1.x, oa1.x); oa1.y = fmaf(av, w1.y, oa1.y);
      oa1.z = fmaf(av, w1.z, oa1.z); oa1.w = fmaf(av, w1.w, oa1.w);
    }
  }
  float* op = out + (size_t)grow * FEA;
  *(float4*)(op + 4 * l) = oa0;
  *(float4*)(op + 256 + 4 * l) = oa1;
}

// ------------------------------------------------------------------
extern "C" void kernel_launch(void* const* d_in, const int* in_sizes, int n_in,
                              void* d_out, int out_size, void* d_ws, size_t ws_size,
                              hipStream_t stream) {
  (void)in_sizes; (void)n_in; (void)out_size;
  const float* x = (const float*)d_in[0];
  const float* W = (const float*)d_in[1];
  float* out = (float*)d_out;
  float* att = (float*)d_out + (size_t)NROWS * FEA;

  const size_t w_need = (size_t)PLW * 2 * sizeof(ushort_t);  // 4 MB
  if (ws_size >= w_need) {
    ushort_t* xpl = (ushort_t*)d_out;  // out region: exactly fits 2 x-planes
    ushort_t* wpl = (ushort_t*)d_ws;
    split_x<<<2048, 256, 0, stream>>>(x, xpl);
    split_w<<<(int)(PLW / 4 / 256), 256, 0, stream>>>(W, wpl);
    gemm_mfma9<<<2048, 512, 0, stream>>>(xpl, wpl, att);
  } else {
    dim3 g1(NROWS / 128, (MEM + 127) / 128);
    gemm_scores<<<g1, 256, 0, stream>>>(x, W, att);
  }
  softmax_shrink_out<<<NROWS / 8, 512, 0, stream>>>(W, out, att);
}

// Round 12
// 702.861 us; speedup vs baseline: 2.3176x; 1.0173x over previous
//
#include <hip/hip_runtime.h>

#define NROWS 65536
#define FEA   512
#define MEM   2000
#define MEMP  2048
#define LAMBDA 0.0025f
#define EPS    1e-12f

#define PLX ((long)NROWS * FEA)   // elements per x plane
#define PLW ((long)MEMP * FEA)    // elements per W plane

typedef unsigned short ushort_t;
typedef __attribute__((ext_vector_type(8))) short bf16x8;
typedef __attribute__((ext_vector_type(4))) float f32x4;

// ---------- bf16 split helpers (RNE) ----------
__device__ inline ushort_t f2bf(float f) {
  unsigned int u = __float_as_uint(f);
  unsigned int r = (u + 0x7FFFu + ((u >> 16) & 1u)) >> 16;
  return (ushort_t)r;
}
__device__ inline float bf2f(ushort_t h) {
  return __uint_as_float(((unsigned int)h) << 16);
}

__device__ inline void gload_lds16(const void* g, void* l) {
  __builtin_amdgcn_global_load_lds(
      (const __attribute__((address_space(1))) unsigned int*)g,
      (__attribute__((address_space(3))) unsigned int*)l, 16, 0, 0);
}

// ------------------------------------------------------------------
// K0a: split x (fp32) -> xh, xl bf16 planes (stored in out region)
// ------------------------------------------------------------------
__global__ __launch_bounds__(256) void split_x(const float* __restrict__ x,
                                               ushort_t* __restrict__ xpl) {
  const long n4 = PLX / 4;
  long i = (long)blockIdx.x * 256 + threadIdx.x;
  const long stride = (long)gridDim.x * 256;
  for (; i < n4; i += stride) {
    float4 v = ((const float4*)x)[i];
    float f[4] = {v.x, v.y, v.z, v.w};
    ushort_t hh[4], ll[4];
#pragma unroll
    for (int j = 0; j < 4; ++j) {
      hh[j] = f2bf(f[j]);
      ll[j] = f2bf(f[j] - bf2f(hh[j]));
    }
    ushort4 h; h.x = hh[0]; h.y = hh[1]; h.z = hh[2]; h.w = hh[3];
    ushort4 l; l.x = ll[0]; l.y = ll[1]; l.z = ll[2]; l.w = ll[3];
    ((ushort4*)xpl)[i] = h;
    ((ushort4*)(xpl + PLX))[i] = l;
  }
}

// ------------------------------------------------------------------
// K0b: split W -> wh, wl planes, padded to 2048 rows (zeros)
// ------------------------------------------------------------------
__global__ __launch_bounds__(256) void split_w(const float* __restrict__ W,
                                               ushort_t* __restrict__ wpl) {
  long i = (long)blockIdx.x * 256 + threadIdx.x;
  if (i >= PLW / 4) return;
  long row = i / (FEA / 4);
  ushort4 h = {0, 0, 0, 0}, l = {0, 0, 0, 0};
  if (row < MEM) {
    float4 v = ((const float4*)W)[i];
    float f[4] = {v.x, v.y, v.z, v.w};
    ushort_t hh[4], ll[4];
#pragma unroll
    for (int j = 0; j < 4; ++j) {
      hh[j] = f2bf(f[j]);
      ll[j] = f2bf(f[j] - bf2f(hh[j]));
    }
    h.x = hh[0]; h.y = hh[1]; h.z = hh[2]; h.w = hh[3];
    l.x = ll[0]; l.y = ll[1]; l.z = ll[2]; l.w = ll[3];
  }
  ((ushort4*)wpl)[i] = h;
  ((ushort4*)(wpl + PLW))[i] = l;
}

// ------------------------------------------------------------------
// K1: S = x @ W^T, split-bf16 (3 products), 256x256 tile, BK=32,
// 16x16x32 MFMA, conflict-free lane map (r9), 8-PHASE schedule:
// per tile 4 phases = C-quadrants (0,0),(0,1),(1,1),(1,0); each phase
// {reads | stage 1 half-unit | bar | lgkm0+schedbar | 24 MFMA |
// [vmcnt(2)@p0 / vmcnt(4)@p3] | bar}. Half-units are quadrant-aligned:
// A-halfH = rows with bit6==H, B-halfH = rows with bit5==H.
// Slot: [256 rows][128 B], phys chunk = c ^ (row&7). LDS 128 KB.
// ------------------------------------------------------------------
template <int MH, int NH>
__device__ __forceinline__ void mfma24(const bf16x8 (&a)[4][2],
                                       const bf16x8 (&b)[2][2],
                                       f32x4 (&acc)[8][4]) {
  __builtin_amdgcn_s_setprio(1);
#pragma unroll
  for (int mi = 0; mi < 4; ++mi)
#pragma unroll
    for (int nf = 0; nf < 2; ++nf)
      acc[MH * 4 + mi][NH * 2 + nf] = __builtin_amdgcn_mfma_f32_16x16x32_bf16(
          a[mi][0], b[nf][0], acc[MH * 4 + mi][NH * 2 + nf], 0, 0, 0);
#pragma unroll
  for (int mi = 0; mi < 4; ++mi)
#pragma unroll
    for (int nf = 0; nf < 2; ++nf)
      acc[MH * 4 + mi][NH * 2 + nf] = __builtin_amdgcn_mfma_f32_16x16x32_bf16(
          a[mi][0], b[nf][1], acc[MH * 4 + mi][NH * 2 + nf], 0, 0, 0);
#pragma unroll
  for (int mi = 0; mi < 4; ++mi)
#pragma unroll
    for (int nf = 0; nf < 2; ++nf)
      acc[MH * 4 + mi][NH * 2 + nf] = __builtin_amdgcn_mfma_f32_16x16x32_bf16(
          a[mi][1], b[nf][0], acc[MH * 4 + mi][NH * 2 + nf], 0, 0, 0);
  __builtin_amdgcn_s_setprio(0);
}

__global__ __launch_bounds__(512, 2) void gemm_mfma10(
    const ushort_t* __restrict__ xpl, const ushort_t* __restrict__ wpl,
    float* __restrict__ S) {
  __shared__ alignas(16) ushort_t lds[65536];  // A 2-slot 64 KB | B 2-slot 64 KB

  const int tid = threadIdx.x;
  const int wid = tid >> 6, lane = tid & 63;
  const int l15 = lane & 15, lq = lane >> 4, rx = l15 & 7;
  const int wm = wid >> 2, wn = wid & 3;       // 2M x 4N waves

  // XCD-chunked bijective swizzle (2048 wgs): proven 197 MB fetch
  int wg = blockIdx.x;
  int xcd = wg & 7, idx = wg >> 3;
  const int mt = xcd * 32 + (idx >> 3);
  const int nt = idx & 7;
  const long rm0 = (long)mt * 256;
  const long cn0 = (long)nt * 256;

  // --- per-lane LDS read bases (ushort units) ---
  const int aB0 = (wm * 128 + l15) * 64 + ((lq ^ rx) * 8);
  const int aB1 = aB0 ^ 32;                    // plane-1: byte ^64
  const int bB0 = 32768 + (wn * 64 + l15) * 64 + ((lq ^ rx) * 8);
  const int bB1 = bB0 ^ 32;

  // --- per-thread stage offsets (half-unit granularity, H additive) ---
  int aDst[2], aSrc[2], bDst[2], bSrc[2];
#pragma unroll
  for (int i = 0; i < 2; ++i) {
    int q = i * 512 + tid;
    // A half-unit: rows with bit6==0: r = (q>=512?128:0) + ((q>>3)&63)
    int rA = ((q >> 9) << 7) + ((q >> 3) & 63);
    int psA = q & 7, lsA = psA ^ (rA & 7);
    aDst[i] = rA * 64 + psA * 8;
    aSrc[i] = (lsA >> 2) * (int)PLX + rA * FEA + (lsA & 3) * 8;
    // B half-unit: rows with bit5==0: r = (q>>8)*64 + ((q>>3)&31)
    int rB = ((q >> 8) << 6) + ((q >> 3) & 31);
    int psB = q & 7, lsB = psB ^ (rB & 7);
    bDst[i] = rB * 64 + psB * 8;
    bSrc[i] = (lsB >> 2) * (int)PLW + rB * FEA + (lsB & 3) * 8;
  }
  const ushort_t* xb = xpl + rm0 * FEA;
  const ushort_t* wb = wpl + cn0 * FEA;

  f32x4 acc[8][4] = {};
  bf16x8 a[4][2], b[2][2];

  // prologue: tile 0 into slot 0, unit order Ah0,Bh0,Ah1,Bh1
#pragma unroll
  for (int i = 0; i < 2; ++i) gload_lds16(xb + aSrc[i], lds + aDst[i]);
#pragma unroll
  for (int i = 0; i < 2; ++i) gload_lds16(wb + bSrc[i], lds + 32768 + bDst[i]);
#pragma unroll
  for (int i = 0; i < 2; ++i) gload_lds16(xb + 64 * FEA + aSrc[i], lds + 4096 + aDst[i]);
#pragma unroll
  for (int i = 0; i < 2; ++i) gload_lds16(wb + 32 * FEA + bSrc[i], lds + 32768 + 2048 + bDst[i]);
  asm volatile("s_waitcnt vmcnt(4)" ::: "memory");
  asm volatile("s_barrier" ::: "memory");

  for (int t = 0; t < 16; ++t) {
    const int so = (t & 1) * 16384;
    const int so2 = so ^ 16384;
    const bool st = (t < 15);
    const ushort_t* xs = xb + (t + 1) * 32;
    const ushort_t* ws = wb + (t + 1) * 32;

    // ===== phase 0: quadrant (0,0); stage A-h0(t+1); vmcnt(2) =====
#pragma unroll
    for (int mi = 0; mi < 4; ++mi) {
      a[mi][0] = *(const bf16x8*)(lds + so + aB0 + mi * 1024);
      a[mi][1] = *(const bf16x8*)(lds + so + aB1 + mi * 1024);
    }
#pragma unroll
    for (int nf = 0; nf < 2; ++nf) {
      b[nf][0] = *(const bf16x8*)(lds + so + bB0 + nf * 1024);
      b[nf][1] = *(const bf16x8*)(lds + so + bB1 + nf * 1024);
    }
    if (st) {
#pragma unroll
      for (int i = 0; i < 2; ++i) gload_lds16(xs + aSrc[i], lds + so2 + aDst[i]);
    }
    asm volatile("s_waitcnt lgkmcnt(8)" ::: "memory");
    asm volatile("s_barrier" ::: "memory");
    asm volatile("s_waitcnt lgkmcnt(0)" ::: "memory");
    __builtin_amdgcn_sched_barrier(0);
    mfma24<0, 0>(a, b, acc);
    if (st) asm volatile("s_waitcnt vmcnt(2)" ::: "memory");
    else    asm volatile("s_waitcnt vmcnt(0)" ::: "memory");
    asm volatile("s_barrier" ::: "memory");

    // ===== phase 1: quadrant (0,1); stage B-h0(t+1) =====
#pragma unroll
    for (int nf = 0; nf < 2; ++nf) {
      b[nf][0] = *(const bf16x8*)(lds + so + bB0 + 2048 + nf * 1024);
      b[nf][1] = *(const bf16x8*)(lds + so + bB1 + 2048 + nf * 1024);
    }
    if (st) {
#pragma unroll
      for (int i = 0; i < 2; ++i) gload_lds16(ws + bSrc[i], lds + 32768 + so2 + bDst[i]);
    }
    asm volatile("s_barrier" ::: "memory");
    asm volatile("s_waitcnt lgkmcnt(0)" ::: "memory");
    __builtin_amdgcn_sched_barrier(0);
    mfma24<0, 1>(a, b, acc);
    asm volatile("s_barrier" ::: "memory");

    // ===== phase 2: quadrant (1,1); stage A-h1(t+1) =====
#pragma unroll
    for (int mi = 0; mi < 4; ++mi) {
      a[mi][0] = *(const bf16x8*)(lds + so + aB0 + 4096 + mi * 1024);
      a[mi][1] = *(const bf16x8*)(lds + so + aB1 + 4096 + mi * 1024);
    }
    if (st) {
#pragma unroll
      for (int i = 0; i < 2; ++i) gload_lds16(xs + 64 * FEA + aSrc[i], lds + so2 + 4096 + aDst[i]);
    }
    asm volatile("s_barrier" ::: "memory");
    asm volatile("s_waitcnt lgkmcnt(0)" ::: "memory");
    __builtin_amdgcn_sched_barrier(0);
    mfma24<1, 1>(a, b, acc);
    asm volatile("s_barrier" ::: "memory");

    // ===== phase 3: quadrant (1,0); stage B-h1(t+1); vmcnt(4) =====
#pragma unroll
    for (int nf = 0; nf < 2; ++nf) {
      b[nf][0] = *(const bf16x8*)(lds + so + bB0 + nf * 1024);
      b[nf][1] = *(const bf16x8*)(lds + so + bB1 + nf * 1024);
    }
    if (st) {
#pragma unroll
      for (int i = 0; i < 2; ++i) gload_lds16(ws + 32 * FEA + bSrc[i], lds + 32768 + so2 + 2048 + bDst[i]);
    }
    asm volatile("s_barrier" ::: "memory");
    asm volatile("s_waitcnt lgkmcnt(0)" ::: "memory");
    __builtin_amdgcn_sched_barrier(0);
    mfma24<1, 0>(a, b, acc);
    if (st) {
      asm volatile("s_waitcnt vmcnt(4)" ::: "memory");
      asm volatile("s_barrier" ::: "memory");
    }
  }

  // epilogue: 16x16 C/D layout col = lane&15, row = (lane>>4)*4 + reg
#pragma unroll
  for (int mf = 0; mf < 8; ++mf)
#pragma unroll
    for (int nf = 0; nf < 4; ++nf) {
      int col = (int)cn0 + wn * 64 + nf * 16 + l15;
      if (col < MEM) {
        long rbase = rm0 + wm * 128 + mf * 16 + lq * 4;
#pragma unroll
        for (int r = 0; r < 4; ++r)
          S[(rbase + r) * MEM + col] = acc[mf][nf][r];
      }
    }
}

// ------------------------------------------------------------------
// Fallback fp32 GEMM (used only if ws too small)
// ------------------------------------------------------------------
#define BKF 32
__global__ __launch_bounds__(256) void gemm_scores(
    const float* __restrict__ x, const float* __restrict__ Wt,
    float* __restrict__ S) {
  __shared__ float xs[BKF][129];
  __shared__ float ws[BKF][129];
  const int tid = threadIdx.x;
  const int rm0 = blockIdx.x * 128;
  const int cn0 = blockIdx.y * 128;
  const int tx = tid & 15, ty = tid >> 4;
  const int sr = tid >> 3, kq = tid & 7;
  float acc[8][8];
#pragma unroll
  for (int i = 0; i < 8; ++i)
#pragma unroll
    for (int j = 0; j < 8; ++j) acc[i][j] = 0.f;
  for (int k0 = 0; k0 < FEA; k0 += BKF) {
#pragma unroll
    for (int b = 0; b < 4; ++b) {
      const int row = sr + 32 * b;
      float4 v = *(const float4*)(x + (size_t)(rm0 + row) * FEA + k0 + kq * 4);
      xs[kq * 4 + 0][row] = v.x; xs[kq * 4 + 1][row] = v.y;
      xs[kq * 4 + 2][row] = v.z; xs[kq * 4 + 3][row] = v.w;
      int wr = cn0 + row; wr = (wr < MEM) ? wr : (MEM - 1);
      float4 u = *(const float4*)(Wt + (size_t)wr * FEA + k0 + kq * 4);
      ws[kq * 4 + 0][row] = u.x; ws[kq * 4 + 1][row] = u.y;
      ws[kq * 4 + 2][row] = u.z; ws[kq * 4 + 3][row] = u.w;
    }
    __syncthreads();
#pragma unroll 8
    for (int k = 0; k < BKF; ++k) {
      float a[8], bb[8];
      float4 t0 = *(const float4*)&xs[k][4 * ty];
      float4 t1 = *(const float4*)&xs[k][64 + 4 * ty];
      a[0] = t0.x; a[1] = t0.y; a[2] = t0.z; a[3] = t0.w;
      a[4] = t1.x; a[5] = t1.y; a[6] = t1.z; a[7] = t1.w;
      float4 u0 = *(const float4*)&ws[k][4 * tx];
      float4 u1 = *(const float4*)&ws[k][64 + 4 * tx];
      bb[0] = u0.x; bb[1] = u0.y; bb[2] = u0.z; bb[3] = u0.w;
      bb[4] = u1.x; bb[5] = u1.y; bb[6] = u1.z; bb[7] = u1.w;
#pragma unroll
      for (int i = 0; i < 8; ++i)
#pragma unroll
        for (int j = 0; j < 8; ++j)
          acc[i][j] = fmaf(a[i], bb[j], acc[i][j]);
    }
    __syncthreads();
  }
#pragma unroll
  for (int i = 0; i < 8; ++i) {
    const int row = rm0 + ((i < 4) ? (4 * ty + i) : (64 + 4 * ty + (i - 4)));
    const int c0 = cn0 + 4 * tx;
    const int c1 = cn0 + 64 + 4 * tx;
    if (c0 < MEM) {
      float4 v; v.x = acc[i][0]; v.y = acc[i][1]; v.z = acc[i][2]; v.w = acc[i][3];
      *(float4*)(S + (size_t)row * MEM + c0) = v;
    }
    if (c1 < MEM) {
      float4 v; v.x = acc[i][4]; v.y = acc[i][5]; v.z = acc[i][6]; v.w = acc[i][7];
      *(float4*)(S + (size_t)row * MEM + c1) = v;
    }
  }
}

// ------------------------------------------------------------------
// K2: softmax -> hard shrink -> renorm -> write att + sparse out
// ------------------------------------------------------------------
__global__ __launch_bounds__(512) void softmax_shrink_out(
    const float* __restrict__ Wt, float* __restrict__ out,
    float* __restrict__ att /* raw scores on entry */) {
  __shared__ float sl[8 * MEM];
  const int tid = threadIdx.x;
  const int r0 = blockIdx.x * 8;
  {
    const float* Sblk = att + (size_t)r0 * MEM;
#pragma unroll
    for (int jj = 0; jj < 8; ++jj) {
      int q = tid + 512 * jj;
      if (q < (8 * MEM) / 4) {
        float4 v = *(const float4*)(Sblk + 4 * q);
        *(float4*)&sl[4 * q] = v;
      }
    }
  }
  __syncthreads();
  const int w = tid >> 6;
  const int l = tid & 63;
  float* row_lds = &sl[w * MEM];
  const int grow = r0 + w;

  float m = -INFINITY;
  for (int j = 0; j < 32; ++j) {
    int c = l + 64 * j;
    if (c < MEM) m = fmaxf(m, row_lds[c]);
  }
#pragma unroll
  for (int off = 32; off; off >>= 1) m = fmaxf(m, __shfl_xor(m, off));

  float s = 0.f;
  for (int j = 0; j < 32; ++j) {
    int c = l + 64 * j;
    if (c < MEM) {
      float e = expf(row_lds[c] - m);
      row_lds[c] = e;
      s += e;
    }
  }
#pragma unroll
  for (int off = 32; off; off >>= 1) s += __shfl_xor(s, off);

  float qs = 0.f;
  for (int j = 0; j < 32; ++j) {
    int c = l + 64 * j;
    if (c < MEM) {
      float p = row_lds[c] / s;
      float d = p - LAMBDA;
      float q = fmaxf(d, 0.f) * p / (fabsf(d) + EPS);
      row_lds[c] = q;
      qs += q;
    }
  }
#pragma unroll
  for (int off = 32; off; off >>= 1) qs += __shfl_xor(qs, off);
  const float denom = fmaxf(qs, EPS);

  float4 oa0 = {0.f, 0.f, 0.f, 0.f};
  float4 oa1 = {0.f, 0.f, 0.f, 0.f};
  for (int j = 0; j < 32; ++j) {
    int c = l + 64 * j;
    float a = 0.f;
    if (c < MEM) {
      a = row_lds[c] / denom;
      att[(size_t)grow * MEM + c] = a;
    }
    unsigned long long msk = __ballot(a > 0.f);
    while (msk) {
      int b = __ffsll(msk) - 1;
      msk &= msk - 1;
      float av = __shfl(a, b);
      int cc = b + 64 * j;
      const float* wp = Wt + (size_t)cc * FEA;
      float4 w0 = *(const float4*)(wp + 4 * l);
      float4 w1 = *(const float4*)(wp + 256 + 4 * l);
      oa0.x = fmaf(av, w0.x, oa0.x); oa0.y = fmaf(av, w0.y, oa0.y);
      oa0.z = fmaf(av, w0.z, oa0.z); oa0.w = fmaf(av, w0.w, oa0.w);
      oa1.x = fmaf(av, w1.x, oa1.x); oa1.y = fmaf(av, w1.y, oa1.y);
      oa1.z = fmaf(av, w1.z, oa1.z); oa1.w = fmaf(av, w1.w, oa1.w);
    }
  }
  float* op = out + (size_t)grow * FEA;
  *(float4*)(op + 4 * l) = oa0;
  *(float4*)(op + 256 + 4 * l) = oa1;
}

// ------------------------------------------------------------------
extern "C" void kernel_launch(void* const* d_in, const int* in_sizes, int n_in,
                              void* d_out, int out_size, void* d_ws, size_t ws_size,
                              hipStream_t stream) {
  (void)in_sizes; (void)n_in; (void)out_size;
  const float* x = (const float*)d_in[0];
  const float* W = (const float*)d_in[1];
  float* out = (float*)d_out;
  float* att = (float*)d_out + (size_t)NROWS * FEA;

  const size_t w_need = (size_t)PLW * 2 * sizeof(ushort_t);  // 4 MB
  if (ws_size >= w_need) {
    ushort_t* xpl = (ushort_t*)d_out;  // out region: exactly fits 2 x-planes
    ushort_t* wpl = (ushort_t*)d_ws;
    split_x<<<2048, 256, 0, stream>>>(x, xpl);
    split_w<<<(int)(PLW / 4 / 256), 256, 0, stream>>>(W, wpl);
    gemm_mfma10<<<2048, 512, 0, stream>>>(xpl, wpl, att);
  } else {
    dim3 g1(NROWS / 128, (MEM + 127) / 128);
    gemm_scores<<<g1, 256, 0, stream>>>(x, W, att);
  }
  softmax_shrink_out<<<NROWS / 8, 512, 0, stream>>>(W, out, att);
}